// Round 12
// baseline (175.715 us; speedup 1.0000x reference)
//
#include <hip/hip_runtime.h>

#define B 8
#define N 25200
#define ROW 85
#define NC 80
#define K 2048
#define MAXDET 300
#define NBUCKET 4096
#define CAND_CAP 4096
#define NCHUNK 32   /* K/64 */
#define STILE 64    /* score tile rows */

// ---------------------------------------------------------------------------
// Kernel 1: score/cls per box + xyxy boxes4 (bit-identical box math).
// ---------------------------------------------------------------------------
__global__ void __launch_bounds__(256)
nms_score_kernel(const float* __restrict__ x,
                 float* __restrict__ scores,
                 int* __restrict__ cls_id,
                 float4* __restrict__ boxes4) {
    int b = blockIdx.y;
    int i0 = blockIdx.x * STILE;
    int rows = N - i0; if (rows > STILE) rows = STILE;
    __shared__ float lx[STILE * ROW];   // 21760 B
    {
        const float4* s4 = (const float4*)(x + ((size_t)b * N + i0) * ROW);
        float4* d4 = (float4*)lx;
        int nv = rows * ROW / 4;        // 1360 or 1020 (both exact)
        for (int k = threadIdx.x; k < nv; k += 256) d4[k] = s4[k];
    }
    __syncthreads();
    int g = threadIdx.x >> 2;          // box in tile
    int q = threadIdx.x & 3;
    if (g >= rows) return;             // uniform across the 4-lane group
    const float* p = lx + g * ROW;
    float obj = p[4];
    float best = -1e30f;
    int bc = 127;
    if (obj > 0.3f) {
        #pragma unroll
        for (int k = 0; k < 20; ++k) {
            int c = q + 4 * k;
            float v = __fmul_rn(p[5 + c], obj);   // exact, no FMA
            if (v > best) { best = v; bc = c; }   // strict >: in-lane first-max
        }
    }
    #pragma unroll
    for (int m = 1; m < 4; m <<= 1) {   // combine: higher v, tie -> smaller class
        float ov = __shfl_xor(best, m, 64);
        int   oc = __shfl_xor(bc, m, 64);
        if (ov > best || (ov == best && oc < bc)) { best = ov; bc = oc; }
    }
    if (q == 0) {
        int i = i0 + g;
        float score = (obj > 0.3f && best > 0.3f) ? best : -1.0f;
        scores[b * N + i] = score;
        cls_id[b * N + i] = (bc == 127) ? 0 : bc;
        float cx = p[0], cy = p[1], w = p[2], h = p[3];
        float hx = __fmul_rn(w, 0.5f);
        float hy = __fmul_rn(h, 0.5f);
        boxes4[b * N + i] = make_float4(__fsub_rn(cx, hx), __fsub_rn(cy, hy),
                                        __fadd_rn(cx, hx), __fadd_rn(cy, hy));
    }
}

// ---------------------------------------------------------------------------
// Kernel 2 (tail): 8 blocks x 1024 threads, ONE block per batch — zero
// cross-block synchronization (R10 measured the cross-XCD atomic finisher
// protocol as the dominant residual cost). Pipeline per block:
//   zero -> histogram -> scan -> placement -> per-bucket key sort
//   -> LDS->LDS key copy -> class-mask build
//   -> each wave: 5 class-NMS rounds (c = round*16 + wv), kept bits OR'd
//      into LDS lkeep
//   -> one barrier -> wave 0 kept-prefixes -> all 16 waves emit dets/flags.
// Key construction, sort, compaction, NMS fp sequence, and output slot
// logic byte-identical to R10 (absmax 0.0 structurally).
// ---------------------------------------------------------------------------
__global__ void __launch_bounds__(1024, 1)
nms_tail_kernel(const float* __restrict__ scores,
                const float4* __restrict__ boxes4,
                const int* __restrict__ cls_id,
                float* __restrict__ out) {
    __shared__ union {
        struct {   // SELECT phase: 56 KB
            unsigned loff[NBUCKET];              // 16 KB hist -> start ranks
            unsigned lcnt16[NBUCKET / 2];        // 8 KB packed u16 cursors
            unsigned long long lk[CAND_CAP];     // 32 KB sort keys @ byte 24K
        } s;
        struct {   // NMS phase: ~37 KB
            unsigned long long keys[K];          // 16 KB sorted keys @ byte 0
            unsigned long long lcm[NC * NCHUNK]; // 20 KB class masks @ 16K
            unsigned long long lkeep[NCHUNK];    // block-local kept bits
            unsigned long long kept[NCHUNK];     // output: kept words
            unsigned kcpref[NCHUNK];             // output: kept prefix
            int total;                           // output: total kept
        } c;
    } U;
    __shared__ unsigned wsum[16];

    int b = blockIdx.x;
    int t = threadIdx.x;
    int ln = t & 63, wv = t >> 6;
    unsigned long long below = (ln == 0) ? 0ULL : (~0ULL >> (64 - ln));
    constexpr int NITER = (N + 1023) / 1024;    // 25

    // ================= SELECT phase =================
    {   // zero histogram + cursors (24 KB)
        uint4 z = {0u, 0u, 0u, 0u};
        uint4* d1 = (uint4*)U.s.loff;
        for (int k = t; k < (NBUCKET + NBUCKET / 2) / 4; k += 1024) d1[k] = z;
    }
    for (int k = t; k < CAND_CAP; k += 1024) U.s.lk[k] = 0ULL;
    __syncthreads();

    // histogram pass: single global read, cache scores in registers
    float sreg[NITER];
    #pragma unroll
    for (int r = 0; r < NITER; ++r) {
        int i = t + r * 1024;
        float s = (i < N) ? scores[b * N + i] : -1.0f;
        sreg[r] = s;
        if (s > 0.0f) {
            int q = (int)(__fmul_rn(s, 4096.0f));
            if (q > NBUCKET - 1) q = NBUCKET - 1;
            atomicAdd(&U.s.loff[q], 1u);
        }
    }
    __syncthreads();

    // descending exclusive scan in place: loff[q] = count in buckets > q.
    // thread t owns buckets 4095-4t .. 4092-4t (uint4 index 1023-t).
    {
        unsigned v[4];
        unsigned A4 = (unsigned)(NBUCKET / 4 - 1 - t);
        {
            uint4 u0 = ((uint4*)U.s.loff)[A4];
            v[0] = u0.w; v[1] = u0.z; v[2] = u0.y; v[3] = u0.x;
        }
        unsigned S = v[0] + v[1] + v[2] + v[3];
        unsigned pref = S;
        #pragma unroll
        for (int o = 1; o < 64; o <<= 1) { unsigned u = __shfl_up(pref, o, 64); if (ln >= o) pref += u; }
        if (ln == 63) wsum[wv] = pref;
        __syncthreads();
        unsigned wbase = 0;
        for (int w = 0; w < wv; ++w) wbase += wsum[w];
        unsigned running = wbase + pref - S;
        unsigned o[4];
        #pragma unroll
        for (int k = 0; k < 4; ++k) { o[3 - k] = running; running += v[k]; }
        ((uint4*)U.s.loff)[A4] = make_uint4(o[0], o[1], o[2], o[3]);
    }
    __syncthreads();

    // placement (counting sort) from register-cached scores
    #pragma unroll
    for (int r = 0; r < NITER; ++r) {
        float s = sreg[r];
        if (s > 0.0f) {
            int i = t + r * 1024;
            int q = (int)(__fmul_rn(s, 4096.0f));
            if (q > NBUCKET - 1) q = NBUCKET - 1;
            unsigned start = U.s.loff[q];
            if (start < CAND_CAP) {
                unsigned sh = (q & 1) * 16;
                unsigned old = atomicAdd(&U.s.lcnt16[q >> 1], 1u << sh);
                unsigned rank = (old >> sh) & 0xFFFFu;
                unsigned pos = start + rank;
                if (pos < CAND_CAP) {
                    unsigned long long key =
                        ((unsigned long long)__float_as_uint(s) << 32) | (unsigned)(~i);
                    U.s.lk[pos] = key;
                }
            }
        }
    }
    __syncthreads();

    // per-bucket insertion sort (descending keys), disjoint ranges
    for (int q = t; q < NBUCKET; q += 1024) {
        unsigned start = U.s.loff[q];
        if (start < CAND_CAP) {
            unsigned cc = (U.s.lcnt16[q >> 1] >> ((q & 1) * 16)) & 0xFFFFu;
            unsigned m = cc;
            if (m > CAND_CAP - start) m = CAND_CAP - start;
            if (m >= 2) {
                for (unsigned a = start + 1; a < start + m; ++a) {
                    unsigned long long kv = U.s.lk[a];
                    unsigned p2 = a;
                    while (p2 > start && U.s.lk[p2 - 1] < kv) { U.s.lk[p2] = U.s.lk[p2 - 1]; --p2; }
                    U.s.lk[p2] = kv;
                }
            }
        }
    }
    __syncthreads();

    // ================= transition: keys <- lk (disjoint LDS regions) =======
    // keys @ bytes [0,16K) ; lk @ bytes [24K,56K) -> safe concurrent copy.
    for (int r = t; r < K; r += 1024) U.c.keys[r] = U.s.lk[r];
    __syncthreads();
    // lcm/lkeep overlap dead lcnt16/lk only after the copy barrier.
    for (int k = t; k < NC * NCHUNK; k += 1024) U.c.lcm[k] = 0ULL;
    if (t < NCHUNK) U.c.lkeep[t] = 0ULL;
    __syncthreads();

    // parallel class-mask build (1024 threads x 2 ranks)
    for (int r = t; r < K; r += 1024) {
        unsigned long long key = U.c.keys[r];
        if (key != 0ULL) {
            int idx = (int)(~(unsigned)key);
            int cc = cls_id[b * N + idx];
            atomicOr(&U.c.lcm[cc * NCHUNK + (r >> 6)], 1ULL << (r & 63));
        }
    }
    __syncthreads();

    // ================= per-wave class NMS: 5 rounds, kept -> LDS ==========
    for (int round = 0; round < 5; ++round) {
        int c = round * 16 + wv;     // this wave's class this round, 0..79

        // register compaction: lane ln -> ln-th member (rank-ascending)
        int n = 0, r = -1, ch_i = -1, myk = -1;
        unsigned long long mych = 0ULL;
        for (int ch = 0; ch < NCHUNK; ++ch) {
            unsigned long long m = U.c.lcm[c * NCHUNK + ch];   // wave-uniform
            int cnt = __popcll(m);
            if (myk < 0 && ln < n + cnt) { mych = m; myk = ln - n; ch_i = ch; }
            n += cnt;
        }
        if (myk >= 0) {
            unsigned long long mm = mych;
            for (int z = 0; z < myk; ++z) mm &= mm - 1;
            r = ch_i * 64 + (int)__builtin_ctzll(mm);
        }

        float shf = __fmul_rn((float)c, 4096.0f);   // class shift (uniform)

        if (n > 0 && n <= 64) {
            // fast path: member ln computes its shifted box in-lane
            float x1 = 0.f, y1 = 0.f, x2 = 0.f, y2 = 0.f, ar = 0.f;
            if (ln < n) {
                unsigned long long key = U.c.keys[r];
                int idx = (int)(~(unsigned)key);
                float4 bb = boxes4[(size_t)b * N + idx];
                x1 = __fadd_rn(bb.x, shf); y1 = __fadd_rn(bb.y, shf);
                x2 = __fadd_rn(bb.z, shf); y2 = __fadd_rn(bb.w, shf);
                ar = __fmul_rn(__fsub_rn(x2, x1), __fsub_rn(y2, y1));
            }
            unsigned long long keepw = (n == 64) ? ~0ULL : ((1ULL << n) - 1ULL);
            for (int i = 0; i < n; ++i) {
                if (!((keepw >> i) & 1ULL)) continue;   // uniform
                float bx1 = __shfl(x1, i, 64), by1 = __shfl(y1, i, 64);
                float bx2 = __shfl(x2, i, 64), by2 = __shfl(y2, i, 64);
                float ba  = __shfl(ar, i, 64);
                bool cond = false;
                if (ln > i && ln < n) {
                    float lx = fmaxf(bx1, x1), ly = fmaxf(by1, y1);
                    float rx = fminf(bx2, x2), ry = fminf(by2, y2);
                    float w = fmaxf(__fsub_rn(rx, lx), 0.0f);
                    float h = fmaxf(__fsub_rn(ry, ly), 0.0f);
                    float inter = __fmul_rn(w, h);
                    float denom = __fadd_rn(__fsub_rn(__fadd_rn(ba, ar), inter), 1e-9f);
                    cond = __fdiv_rn(inter, denom) > 0.6f;   // exact ref order
                }
                keepw &= ~__ballot(cond);
            }
            if (ln < n && ((keepw >> ln) & 1ULL))
                atomicOr(&U.c.lkeep[r >> 6], 1ULL << (r & 63));   // LDS
        } else if (n > 64) {
            // general path (n > 64): wave-local register-distributed keep
            // bits. Correctness-only; unreachable for this data distribution.
            unsigned long long membw = (ln < NCHUNK) ? U.c.lcm[c * NCHUNK + ln] : 0ULL;
            unsigned long long keepw2 = membw;
            for (int i = 0; i < K; ++i) {
                int ch = i >> 6;
                unsigned long long mw = __shfl(membw, ch, 64);
                unsigned long long kw = __shfl(keepw2, ch, 64);
                unsigned long long bi = 1ULL << (i & 63);
                if (!(mw & kw & bi)) continue;   // uniform
                unsigned long long keyi = U.c.keys[i];             // uniform
                int idxi = (int)(~(unsigned)keyi);
                float4 bi4 = boxes4[(size_t)b * N + idxi];
                float bx1 = __fadd_rn(bi4.x, shf), by1 = __fadd_rn(bi4.y, shf);
                float bx2 = __fadd_rn(bi4.z, shf), by2 = __fadd_rn(bi4.w, shf);
                float ba = __fmul_rn(__fsub_rn(bx2, bx1), __fsub_rn(by2, by1));
                for (int c2 = ch; c2 < NCHUNK; ++c2) {
                    int j = c2 * 64 + ln;
                    unsigned long long mw2 = __shfl(membw, c2, 64);
                    bool cond = false;
                    if (j > i && ((mw2 >> ln) & 1ULL)) {
                        unsigned long long keyj = U.c.keys[j];
                        int idxj = (int)(~(unsigned)keyj);
                        float4 bj4 = boxes4[(size_t)b * N + idxj];
                        float x1 = __fadd_rn(bj4.x, shf), y1 = __fadd_rn(bj4.y, shf);
                        float x2 = __fadd_rn(bj4.z, shf), y2 = __fadd_rn(bj4.w, shf);
                        float arj = __fmul_rn(__fsub_rn(x2, x1), __fsub_rn(y2, y1));
                        float lx = fmaxf(bx1, x1), ly = fmaxf(by1, y1);
                        float rx = fminf(bx2, x2), ry = fminf(by2, y2);
                        float w = fmaxf(__fsub_rn(rx, lx), 0.0f);
                        float h = fmaxf(__fsub_rn(ry, ly), 0.0f);
                        float inter = __fmul_rn(w, h);
                        float denom = __fadd_rn(__fsub_rn(__fadd_rn(ba, arj), inter), 1e-9f);
                        cond = __fdiv_rn(inter, denom) > 0.6f;
                    }
                    unsigned long long sup = __ballot(cond);
                    if (ln == c2) keepw2 &= ~sup;
                }
            }
            unsigned long long kb = keepw2 & membw;
            if (ln < NCHUNK && kb)
                atomicOr(&U.c.lkeep[ln], kb);   // LDS
        }
    }
    __syncthreads();

    // ================= output phase (whole block) =================
    if (wv == 0) {
        unsigned long long kwv = (ln < NCHUNK) ? U.c.lkeep[ln] : 0ULL;
        unsigned pc = (unsigned)__popcll(kwv);
        unsigned incl = pc;
        #pragma unroll
        for (int o = 1; o < 32; o <<= 1) { unsigned u = __shfl_up(incl, o, 64); if (ln >= o) incl += u; }
        if (ln < NCHUNK) {
            U.c.kept[ln] = kwv;
            U.c.kcpref[ln] = incl - pc;      // exclusive kept prefix
        }
        if (ln == 31) U.c.total = (int)incl; // total kept
    }
    __syncthreads();

    {
        int total = U.c.total;
        float* dets  = out + (size_t)b * MAXDET * 6;
        float* flags = out + (size_t)B * MAXDET * 6 + (size_t)b * MAXDET;
        #pragma unroll
        for (int h = 0; h < 2; ++h) {
            int ch = wv * 2 + h;
            int i = ch * 64 + ln;
            unsigned long long m = U.c.kept[ch];
            bool k = ((m >> ln) & 1ULL) != 0ULL;
            int kp = (int)U.c.kcpref[ch];
            int np = ch * 64 - kp;           // exclusive non-kept prefix
            int slot = k ? (kp + (int)__popcll(m & below))
                         : (total + np + (int)__popcll((~m) & below));
            if (slot < MAXDET) {
                unsigned long long key = U.c.keys[i];
                float s, ox1, oy1, ox2, oy2; int oc;
                if (key == 0ULL) {
                    s = -1.0f; ox1 = oy1 = ox2 = oy2 = 0.0f; oc = 0;
                } else {
                    s = __uint_as_float((unsigned)(key >> 32));
                    int idx = (int)(~(unsigned)key);
                    float4 bb = boxes4[(size_t)b * N + idx];
                    ox1 = bb.x; oy1 = bb.y; ox2 = bb.z; oy2 = bb.w;
                    oc = cls_id[b * N + idx];
                }
                dets[slot * 6 + 0] = ox1;
                dets[slot * 6 + 1] = oy1;
                dets[slot * 6 + 2] = ox2;
                dets[slot * 6 + 3] = oy2;
                dets[slot * 6 + 4] = s;
                dets[slot * 6 + 5] = (float)oc;
                flags[slot] = k ? 1.0f : 0.0f;
            }
        }
    }
}

// ---------------------------------------------------------------------------
extern "C" void kernel_launch(void* const* d_in, const int* in_sizes, int n_in,
                              void* d_out, int out_size, void* d_ws, size_t ws_size,
                              hipStream_t stream) {
    const float* x = (const float*)d_in[0];
    float* out = (float*)d_out;

    char* ws = (char*)d_ws;
    size_t off = 0;
    auto alloc = [&](size_t bytes) -> void* {
        void* p = ws + off;
        off += bytes;
        off = (off + 255) & ~(size_t)255;
        return p;
    };

    float*  scores = (float*)  alloc((size_t)B * N * 4);
    int*    cls_id = (int*)    alloc((size_t)B * N * 4);
    float4* boxes4 = (float4*) alloc((size_t)B * N * 16);
    (void)ws_size; // needs ~2.4 MB

    nms_score_kernel<<<dim3((N + STILE - 1) / STILE, B), 256, 0, stream>>>(
        x, scores, cls_id, boxes4);
    nms_tail_kernel<<<B, 1024, 0, stream>>>(scores, boxes4, cls_id, out);
}